// Round 7
// baseline (130.088 us; speedup 1.0000x reference)
//
#include <hip/hip_runtime.h>

#define N_NODES 20000
#define N_EDGES 50000
#define NPB 16        // nodes per block in k_conv (one MFMA M-tile)

// k_pre role split (blocks)
#define ZB 79         // zero cnt: 79*256 = 20224 >= 20000
#define PB 416        // pack: 416*256 = 106496 = 73728+32768
// k_fused2 role split (blocks)
#define HB 196        // hist: 196*256 >= 50000
#define LB 1250       // lin0: 1250*16 = 20000
#define EB 3125       // edge_t: 3125*16 = 50000

typedef __attribute__((ext_vector_type(8))) short short8;
typedef __attribute__((ext_vector_type(4))) float f32x4;
typedef unsigned int u32;
typedef unsigned short u16;

// byte-address swizzles (keep ds_read_b128 of strided rows conflict-free)
#define SswzB(i, o) (((i) * 2304 + (o)) ^ (((i) & 7) << 4))   // S: 16 rows x 2304 B
#define MswzB(i, o) (((i) * 256 + (o)) ^ (((i) & 7) << 4))    // M|X: 16 rows x 256 B

__device__ inline u16 f2bf(float x) {            // round-to-nearest-even fp32->bf16
    u32 u = __float_as_uint(x);
    return (u16)((u + 0x7FFFu + ((u >> 16) & 1u)) >> 16);
}

// accumulate one edge: acc[k] += t[e][k] * x  (t stored bf16 x16)
__device__ inline void acc_edge(float* acc, const u16* t, float x) {
    uint4 a = *(const uint4*)t, b = *(const uint4*)(t + 8);
    u32 tw[8] = {a.x, a.y, a.z, a.w, b.x, b.y, b.z, b.w};
#pragma unroll
    for (int q = 0; q < 8; ++q) {
        acc[2 * q]     += __uint_as_float(tw[q] << 16) * x;
        acc[2 * q + 1] += __uint_as_float(tw[q] & 0xFFFF0000u) * x;
    }
}

// ---------------- k_pre: zero cnt | pack weights ----------------
__global__ __launch_bounds__(256) void k_pre(
    int* __restrict__ cnt,
    const float* __restrict__ w2, const float* __restrict__ b2, const float* __restrict__ rootw,
    const float* __restrict__ wih, const float* __restrict__ whh,
    u16* __restrict__ Bp1, u16* __restrict__ Bp2) {
    int tid = threadIdx.x;
    int b = blockIdx.x;
    if (b < ZB) {                       // ---- zero dst-degree counters ----
        int n = b * 256 + tid;
        if (n < N_NODES) cnt[n] = 0;
        return;
    }
    b -= ZB;
    {                                   // ---- weight pack (bf16 MFMA B-fragments) ----
        int idx = b * 256 + tid;
        if (idx < 73728) {
            int j = idx & 7, l = (idx >> 3) & 63, rest = idx >> 9;
            int kb = rest % 36, nt = rest / 36;
            int row = kb * 32 + (l >> 4) * 8 + j;
            int col = nt * 16 + (l & 15);
            float v;
            if (row < 1024) v = w2[row * 64 + col];
            else if (row < 1088) v = b2[(row - 1024) * 64 + col];
            else v = rootw[(row - 1088) * 64 + col];
            Bp1[idx] = f2bf(v);
        } else {
            int o = idx - 73728;
            int j = o & 7, l = (o >> 3) & 63, rest = o >> 9;
            int kb = rest & 3, nt = rest >> 2;
            int k2 = kb * 32 + (l >> 4) * 8 + j;
            int c = nt * 16 + (l & 15);
            float v;
            if (k2 < 64) {
                v = (c < 192) ? wih[k2 * 192 + c] : 0.f;
            } else {
                int f = k2 - 64;
                v = (c < 128) ? whh[f * 192 + c] : ((c < 192) ? 0.f : whh[f * 192 + c - 64]);
            }
            Bp2[o] = f2bf(v);
        }
    }
}

// ---------------- fused preprocessing: hist | lin0 | edge_t ----------------
__global__ __launch_bounds__(256) void k_fused2(
    const int* __restrict__ ei, int* __restrict__ cnt,
    const float* __restrict__ h, const float* __restrict__ lin0w, const float* __restrict__ lin0b,
    float* __restrict__ X0,
    const float* __restrict__ eattr, const float* __restrict__ sw, const float* __restrict__ sb,
    const float* __restrict__ w1, const float* __restrict__ b1, u16* __restrict__ t_arr) {
    __shared__ float sh[16][64];
    int tid = threadIdx.x;
    int b = blockIdx.x;

    if (b < HB) {                       // ---- histogram of dst ----
        int e = b * 256 + tid;
        if (e < N_EDGES) atomicAdd(&cnt[ei[N_EDGES + e]], 1);
        return;
    }
    b -= HB;
    int g = tid & 63, q = tid >> 6;
    if (b < LB) {                       // ---- X0 = relu(h @ lin0_w + lin0_b), 16 nodes ----
        int n0 = b * 16;
        for (int i = tid; i < 16 * 64; i += 256) sh[i >> 6][i & 63] = h[n0 * 64 + i];
        __syncthreads();
        for (int j = 0; j < 4; j++) {
            int i = q * 4 + j;
            float acc = lin0b[g];
            for (int f = 0; f < 64; f++) acc += sh[i][f] * lin0w[f * 64 + g];
            X0[(n0 + i) * 64 + g] = acc > 0.f ? acc : 0.f;
        }
        return;
    }
    b -= LB;
    {                                   // ---- t[e,16] = relu(relu(ea@short)@nn1), 16 edges ----
        int e0 = b * 16;
#pragma unroll
        for (int j = 0; j < 4; j++) {
            int r = q * 4 + j;
            int e = e0 + r;
            float a0 = eattr[e * 5 + 0], a1 = eattr[e * 5 + 1], a2 = eattr[e * 5 + 2],
                  a3 = eattr[e * 5 + 3], a4 = eattr[e * 5 + 4];
            float v = sb[g] + a0 * sw[g] + a1 * sw[64 + g] + a2 * sw[128 + g]
                    + a3 * sw[192 + g] + a4 * sw[256 + g];
            sh[r][g] = v > 0.f ? v : 0.f;
        }
        __syncthreads();
        if (g < 16) {
#pragma unroll
            for (int j = 0; j < 4; j++) {
                int r = q * 4 + j;
                float acc = b1[g];
                for (int c = 0; c < 64; c++) acc += sh[r][c] * w1[c * 16 + g];
                float t = acc > 0.f ? acc : 0.f;
                t_arr[(size_t)(e0 + r) * 16 + g] = f2bf(t);
            }
        }
    }
}

// ---------------- exclusive scan over counts (single block, shfl-based) ----------------
__global__ __launch_bounds__(1024) void k_scan(const int* __restrict__ cnt, int* __restrict__ off,
                                               int* __restrict__ cursor, float* __restrict__ cntf) {
    __shared__ int wsum[16], woff[16];
    const int PT = 20;                  // 1024*20 = 20480 >= 20000
    int tid = threadIdx.x, lane = tid & 63, w = tid >> 6;
    int base = tid * PT;
    int loc[PT];
    int sum = 0;
#pragma unroll
    for (int q = 0; q < PT; ++q) {
        int n = base + q;
        int v = (n < N_NODES) ? cnt[n] : 0;
        loc[q] = sum;
        sum += v;
    }
    int inc = sum;
#pragma unroll
    for (int d = 1; d < 64; d <<= 1) {
        int t = __shfl_up(inc, d, 64);
        if (lane >= d) inc += t;
    }
    if (lane == 63) wsum[w] = inc;
    __syncthreads();
    if (w == 0 && lane < 16) {
        int v = wsum[lane];
        int iv = v;
#pragma unroll
        for (int d = 1; d < 16; d <<= 1) {
            int t = __shfl_up(iv, d, 64);
            if (lane >= d) iv += t;
        }
        woff[lane] = iv - v;
        if (lane == 15) wsum[15] = iv;   // grand total
    }
    __syncthreads();
    int excl = woff[w] + (inc - sum);
#pragma unroll
    for (int q = 0; q < PT; ++q) {
        int n = base + q;
        if (n < N_NODES) {
            int o = excl + loc[q];
            int v = ((q + 1 < PT) ? loc[q + 1] : sum) - loc[q];
            off[n] = o;
            cursor[n] = o;
            cntf[n] = v > 0 ? (float)v : 1.0f;
        }
    }
    if (tid == 0) off[N_NODES] = wsum[15];
}

// ---------------- scatter: grouped-by-dst (src, edge) pairs ----------------
__global__ __launch_bounds__(256) void k_scatter(const int* __restrict__ ei, int* __restrict__ cursor,
                                                 int2* __restrict__ edata) {
    int e = blockIdx.x * 256 + threadIdx.x;
    if (e < N_EDGES) {
        int d = ei[N_EDGES + e];
        int p = atomicAdd(&cursor[d], 1);
        edata[p] = make_int2(ei[e], e);
    }
}

// ---------------- fused conv + GRU (MFMA), one iteration ----------------
__global__ __launch_bounds__(256, 4) void k_conv(
    const float* __restrict__ Xprev, float* __restrict__ Xout,
    const u16* __restrict__ t_arr, const int2* __restrict__ edata,
    const int* __restrict__ off, const float* __restrict__ cntf,
    const u16* __restrict__ Bp1, const u16* __restrict__ Bp2,
    const float* __restrict__ convb,
    const float* __restrict__ bih, const float* __restrict__ bhh) {
    __shared__ __align__(16) char smem[40960];
    char* Sb = smem;                 // S: 16 nodes x 1152 bf16 (swizzled)   [36864 B]
    char* Mb = smem + 36864;         // [M|X]: 16 nodes x 128 bf16 (swizzled) [4096 B]
    float* G = (float*)smem;         // gate sums: 16 x 260 f32, aliases S

    int tid = threadIdx.x;
    int g = tid & 63;
    int wq = tid >> 6;
    int m16 = g & 15, hi4 = g >> 4;
    int n0 = blockIdx.x * NPB;

    // ---- hoisted per-node metadata: one latency round for all 4 nodes ----
    int e0v[4], e1v[4];
    float xr4[4], ic4[4];
#pragma unroll
    for (int jj = 0; jj < 4; ++jj) {
        int n = n0 + wq * 4 + jj;
        e0v[jj] = __builtin_amdgcn_readfirstlane(off[n]);
        e1v[jj] = __builtin_amdgcn_readfirstlane(off[n + 1]);
        xr4[jj] = Xprev[n * 64 + g];
        ic4[jj] = 1.0f / cntf[n];
    }

    // ---- phase 1: pair-interleaved edge gather (2 nodes advance together) ----
#pragma unroll
    for (int pair = 0; pair < 2; ++pair) {
        const int jA = pair * 2, jB = jA + 1;
        const int iA = wq * 4 + jA, iB = iA + 1;
        float accA[16], accB[16];
#pragma unroll
        for (int k = 0; k < 16; ++k) { accA[k] = 0.f; accB[k] = 0.f; }
        float sxA = 0.f, sxB = 0.f;
        int pA = e0v[jA], pB = e0v[jB];
        const int endA = e1v[jA];
        const int endB = e1v[jB];
        while ((pA < endA) | (pB < endB)) {
            int mA = endA - pA, mB = endB - pB;
            int2 eA0, eA1, eA2, eA3, eB0, eB1, eB2, eB3;
            float xA0 = 0.f, xA1 = 0.f, xA2 = 0.f, xA3 = 0.f;
            float xB0 = 0.f, xB1 = 0.f, xB2 = 0.f, xB3 = 0.f;
            if (mA > 0) {               // issue A's edata batch
                eA0 = edata[pA];
                eA1 = edata[pA + (mA > 1 ? 1 : 0)];
                eA2 = edata[pA + (mA > 2 ? 2 : 0)];
                eA3 = edata[pA + (mA > 3 ? 3 : 0)];
            }
            if (mB > 0) {               // issue B's edata batch (overlaps A's)
                eB0 = edata[pB];
                eB1 = edata[pB + (mB > 1 ? 1 : 0)];
                eB2 = edata[pB + (mB > 2 ? 2 : 0)];
                eB3 = edata[pB + (mB > 3 ? 3 : 0)];
            }
            if (mA > 0) {               // issue A's x batch
                xA0 = Xprev[eA0.x * 64 + g];
                xA1 = mA > 1 ? Xprev[eA1.x * 64 + g] : 0.f;
                xA2 = mA > 2 ? Xprev[eA2.x * 64 + g] : 0.f;
                xA3 = mA > 3 ? Xprev[eA3.x * 64 + g] : 0.f;
            }
            if (mB > 0) {               // issue B's x batch (overlaps A's)
                xB0 = Xprev[eB0.x * 64 + g];
                xB1 = mB > 1 ? Xprev[eB1.x * 64 + g] : 0.f;
                xB2 = mB > 2 ? Xprev[eB2.x * 64 + g] : 0.f;
                xB3 = mB > 3 ? Xprev[eB3.x * 64 + g] : 0.f;
            }
            if (mA > 0) {
                acc_edge(accA, t_arr + (size_t)eA0.y * 16, xA0);
                acc_edge(accA, t_arr + (size_t)eA1.y * 16, xA1);
                acc_edge(accA, t_arr + (size_t)eA2.y * 16, xA2);
                acc_edge(accA, t_arr + (size_t)eA3.y * 16, xA3);
                sxA += xA0 + xA1 + xA2 + xA3;
                pA += 4;
            }
            if (mB > 0) {
                acc_edge(accB, t_arr + (size_t)eB0.y * 16, xB0);
                acc_edge(accB, t_arr + (size_t)eB1.y * 16, xB1);
                acc_edge(accB, t_arr + (size_t)eB2.y * 16, xB2);
                acc_edge(accB, t_arr + (size_t)eB3.y * 16, xB3);
                sxB += xB0 + xB1 + xB2 + xB3;
                pB += 4;
            }
        }
        float icA = ic4[jA], icB = ic4[jB];
#pragma unroll
        for (int k = 0; k < 16; ++k) {
            *(u16*)(Sb + SswzB(iA, k * 128 + g * 2)) = f2bf(accA[k] * icA);
            *(u16*)(Sb + SswzB(iB, k * 128 + g * 2)) = f2bf(accB[k] * icB);
        }
        *(u16*)(Sb + SswzB(iA, 2048 + g * 2)) = f2bf(sxA * icA);
        *(u16*)(Sb + SswzB(iB, 2048 + g * 2)) = f2bf(sxB * icB);
        *(u16*)(Sb + SswzB(iA, 2176 + g * 2)) = f2bf(xr4[jA]);
        *(u16*)(Sb + SswzB(iB, 2176 + g * 2)) = f2bf(xr4[jB]);
        *(u16*)(Mb + MswzB(iA, 128 + g * 2)) = f2bf(xr4[jA]);
        *(u16*)(Mb + MswzB(iB, 128 + g * 2)) = f2bf(xr4[jB]);
    }
    __syncthreads();

    // ---- GEMM1: [16 x 1152] @ [1152 x 64], 4-deep register pipeline ----
    f32x4 d = {0.f, 0.f, 0.f, 0.f};
    {
        const char* bp = (const char*)Bp1 + ((size_t)(wq * 36) * 64 + g) * 16;  // kb stride 1024 B
        short8 aC[4], bC[4], aN[4], bN[4];
#pragma unroll
        for (int c = 0; c < 4; ++c) {
            aC[c] = *(const short8*)(Sb + SswzB(m16, c * 64 + hi4 * 16));
            bC[c] = *(const short8*)(bp + (size_t)c * 1024);
        }
#pragma unroll
        for (int blk = 0; blk < 9; ++blk) {
            if (blk < 8) {
#pragma unroll
                for (int c = 0; c < 4; ++c) {
                    int kb = blk * 4 + 4 + c;
                    aN[c] = *(const short8*)(Sb + SswzB(m16, kb * 64 + hi4 * 16));
                    bN[c] = *(const short8*)(bp + (size_t)kb * 1024);
                }
            }
#pragma unroll
            for (int c = 0; c < 4; ++c)
                d = __builtin_amdgcn_mfma_f32_16x16x32_bf16(aC[c], bC[c], d, 0, 0, 0);
#pragma unroll
            for (int c = 0; c < 4; ++c) { aC[c] = aN[c]; bC[c] = bN[c]; }
        }
    }
    {
        float cb = convb[wq * 16 + m16];
#pragma unroll
        for (int r = 0; r < 4; ++r) {
            float m = d[r] + cb;
            m = m > 0.f ? m : 0.f;       // relu -> M
            int row = hi4 * 4 + r, col = wq * 16 + m16;
            *(u16*)(Mb + MswzB(row, col * 2)) = f2bf(m);
        }
    }
    __syncthreads();   // M complete; all S reads done (G may alias S now)

    // ---- GEMM2: [16 x 128] @ [128 x 256] ; wave wq owns gate wq ----
    short8 a2[4];
#pragma unroll
    for (int kb = 0; kb < 4; ++kb)
        a2[kb] = *(const short8*)(Mb + MswzB(m16, kb * 64 + hi4 * 16));
    f32x4 e4[4];
#pragma unroll
    for (int q = 0; q < 4; ++q) { e4[q].x = 0.f; e4[q].y = 0.f; e4[q].z = 0.f; e4[q].w = 0.f; }
#pragma unroll
    for (int q = 0; q < 4; ++q)
#pragma unroll
        for (int kb = 0; kb < 4; ++kb) {
            short8 b = *(const short8*)((const char*)Bp2 + ((size_t)((wq * 4 + q) * 4 + kb) * 64 + g) * 16);
            e4[q] = __builtin_amdgcn_mfma_f32_16x16x32_bf16(a2[kb], b, e4[q], 0, 0, 0);
        }
#pragma unroll
    for (int q = 0; q < 4; ++q)
#pragma unroll
        for (int r = 0; r < 4; ++r)
            G[(hi4 * 4 + r) * 260 + wq * 64 + q * 16 + m16] = e4[q][r];
    __syncthreads();

    // ---- GRU elementwise epilogue; wave wq owns nodes 4wq..4wq+3 ----
    float b_r = bih[g] + bhh[g];
    float b_z = bih[64 + g] + bhh[64 + g];
    float b_gi = bih[128 + g];
    float b_gh = bhh[128 + g];
#pragma unroll
    for (int jj = 0; jj < 4; ++jj) {
        int i = wq * 4 + jj;
        int n = n0 + i;
        float rs = G[i * 260 + g] + b_r;
        float zs = G[i * 260 + 64 + g] + b_z;
        float gi = G[i * 260 + 128 + g] + b_gi;
        float gh = G[i * 260 + 192 + g] + b_gh;
        float r = 1.f / (1.f + __expf(-rs));
        float z = 1.f / (1.f + __expf(-zs));
        float aa = gi + r * gh;
        float ex = __expf(2.f * aa);
        float nt = 1.f - 2.f / (ex + 1.f);
        Xout[n * 64 + g] = (1.f - z) * nt + z * xr4[jj];
    }
}

extern "C" void kernel_launch(void* const* d_in, const int* in_sizes, int n_in,
                              void* d_out, int out_size, void* d_ws, size_t ws_size,
                              hipStream_t stream) {
    const float* h     = (const float*)d_in[0];
    const int*   ei    = (const int*)d_in[1];    // [2, E]: row0 = src, row1 = dst
    const float* eattr = (const float*)d_in[3];
    const float* lin0w = (const float*)d_in[4];
    const float* lin0b = (const float*)d_in[5];
    const float* shw   = (const float*)d_in[6];
    const float* shb   = (const float*)d_in[7];
    const float* w1    = (const float*)d_in[8];
    const float* b1    = (const float*)d_in[9];
    const float* w2    = (const float*)d_in[10];
    const float* b2    = (const float*)d_in[11];
    const float* rootw = (const float*)d_in[12];
    const float* convb = (const float*)d_in[13];
    const float* wih   = (const float*)d_in[14];
    const float* whh   = (const float*)d_in[15];
    const float* bih   = (const float*)d_in[16];
    const float* bhh   = (const float*)d_in[17];

    char* ws = (char*)d_ws;
    float* X0     = (float*)ws; ws += (size_t)N_NODES * 64 * 4;
    float* X1     = (float*)ws; ws += (size_t)N_NODES * 64 * 4;
    u16*   t_arr  = (u16*)ws;   ws += (size_t)N_EDGES * 16 * 2;
    u16*   Bp1    = (u16*)ws;   ws += (size_t)73728 * 2;
    u16*   Bp2    = (u16*)ws;   ws += (size_t)32768 * 2;
    int*   cnt    = (int*)ws;   ws += (size_t)N_NODES * 4;
    int*   off    = (int*)ws;   ws += (size_t)(N_NODES + 4) * 4;
    int*   cursor = (int*)ws;   ws += (size_t)N_NODES * 4;
    float* cntf   = (float*)ws; ws += (size_t)N_NODES * 4;
    int2*  edata  = (int2*)ws;  ws += (size_t)N_EDGES * 8;

    k_pre<<<ZB + PB, 256, 0, stream>>>(cnt, w2, b2, rootw, wih, whh, Bp1, Bp2);
    k_fused2<<<HB + LB + EB, 256, 0, stream>>>(ei, cnt, h, lin0w, lin0b, X0,
                                               eattr, shw, shb, w1, b1, t_arr);
    k_scan<<<1, 1024, 0, stream>>>(cnt, off, cursor, cntf);
    k_scatter<<<(N_EDGES + 255) / 256, 256, 0, stream>>>(ei, cursor, edata);

    float* out = (float*)d_out;
    k_conv<<<N_NODES / NPB, 256, 0, stream>>>(X0, X1, t_arr, edata, off, cntf,
                                              Bp1, Bp2, convb, bih, bhh);
    k_conv<<<N_NODES / NPB, 256, 0, stream>>>(X1, out, t_arr, edata, off, cntf,
                                              Bp1, Bp2, convb, bih, bhh);
}